// Round 1
// baseline (91.614 us; speedup 1.0000x reference)
//
#include <hip/hip_runtime.h>
#include <hip/hip_bf16.h>

#define NFEATS 128

typedef __attribute__((ext_vector_type(8))) short bf16x8;
typedef __attribute__((ext_vector_type(4))) float f32x4;

__device__ inline short f2bf(float f) {
    union { float f; unsigned u; } c; c.f = f;
    unsigned u = c.u;
    return (short)((u + 0x7FFFu + ((u >> 16) & 1u)) >> 16);  // RNE
}
__device__ inline float bf2f(short v) {
    union { unsigned u; float f; } c;
    c.u = ((unsigned)(unsigned short)v) << 16;
    return c.f;
}

// Compute Out[n, j] = sum_k X[n,k] * W1[j, k_off+k]  (+ b1[j] if use_bias)
// Out stored as bf16. One block = 128 rows x 128 cols, K=128 in one shot.
__global__ __launch_bounds__(256) void precompute_kernel(
    const float* __restrict__ X, const float* __restrict__ W1,
    const float* __restrict__ b1, short* __restrict__ Out,
    int n_nodes, int k_off, int use_bias)
{
    // W tile in LDS, padded: stride 136 bf16 = 272 B (16B-aligned rows, bank stride 4)
    __shared__ short Wlds[128][136];
    const int tid = threadIdx.x;

    for (int idx = tid; idx < 128 * 128; idx += 256) {
        int j = idx >> 7, k = idx & 127;
        Wlds[j][k] = f2bf(W1[j * 256 + k_off + k]);
    }
    __syncthreads();

    const int wave = tid >> 6, lane = tid & 63;
    const int r16 = lane & 15, q = lane >> 4;       // q in 0..3
    const int row_base = blockIdx.x * 128 + wave * 32;

    // A-fragments: X rows -> bf16, lane holds X[row][kk*32 + q*8 + j], j=0..7
    bf16x8 afrag[2][4];
#pragma unroll
    for (int m = 0; m < 2; ++m) {
        int row = row_base + m * 16 + r16;
        if (row >= n_nodes) row = n_nodes - 1;      // clamp (stores predicated)
        const float* xr = X + (size_t)row * NFEATS;
#pragma unroll
        for (int kk = 0; kk < 4; ++kk) {
            int k0 = kk * 32 + q * 8;
            float4 lo = *(const float4*)(xr + k0);
            float4 hi = *(const float4*)(xr + k0 + 4);
            bf16x8 f;
            f[0] = f2bf(lo.x); f[1] = f2bf(lo.y); f[2] = f2bf(lo.z); f[3] = f2bf(lo.w);
            f[4] = f2bf(hi.x); f[5] = f2bf(hi.y); f[6] = f2bf(hi.z); f[7] = f2bf(hi.w);
            afrag[m][kk] = f;
        }
    }

    // Accumulators init with b1[col] (MFMA C-in accumulates)
    f32x4 acc[2][8];
#pragma unroll
    for (int n = 0; n < 8; ++n) {
        float bv = use_bias ? b1[n * 16 + r16] : 0.f;
        f32x4 init = {bv, bv, bv, bv};
        acc[0][n] = init;
        acc[1][n] = init;
    }

#pragma unroll
    for (int n = 0; n < 8; ++n) {
#pragma unroll
        for (int kk = 0; kk < 4; ++kk) {
            // B operand: lane holds W[col=n*16+r16][k = kk*32 + q*8 + j]
            bf16x8 wf = *(const bf16x8*)&Wlds[n * 16 + r16][kk * 32 + q * 8];
            acc[0][n] = __builtin_amdgcn_mfma_f32_16x16x32_bf16(afrag[0][kk], wf, acc[0][n], 0, 0, 0);
            acc[1][n] = __builtin_amdgcn_mfma_f32_16x16x32_bf16(afrag[1][kk], wf, acc[1][n], 0, 0, 0);
        }
    }

    // C/D layout: col = lane&15, row = (lane>>4)*4 + r
#pragma unroll
    for (int m = 0; m < 2; ++m) {
#pragma unroll
        for (int r = 0; r < 4; ++r) {
            int row = row_base + m * 16 + q * 4 + r;
            if (row < n_nodes) {
                short* orow = Out + (size_t)row * NFEATS;
#pragma unroll
                for (int n = 0; n < 8; ++n)
                    orow[n * 16 + r16] = f2bf(acc[m][n][r]);
            }
        }
    }
}

// Edge stage: score[e] = dot(relu(A[src[e]] + B[dst[e]]), w2) + b2
// One quarter-wave (16 lanes) per edge; lane reads 8 bf16 of A and of B (16B each).
__global__ __launch_bounds__(256) void edge_kernel(
    const short* __restrict__ A, const short* __restrict__ B,
    const int* __restrict__ src, const int* __restrict__ dst,
    const float* __restrict__ W2, const float* __restrict__ b2,
    float* __restrict__ out, int n_edges)
{
    const int t = blockIdx.x * 256 + threadIdx.x;
    const int lane16 = threadIdx.x & 15;

    float w2v[8];
#pragma unroll
    for (int j = 0; j < 8; ++j) w2v[j] = W2[lane16 * 8 + j];
    const float b2v = b2[0];

    const int qw = t >> 4;
    const int nqw = (gridDim.x * 256) >> 4;

    for (int e = qw; e < n_edges; e += nqw) {
        int s = src[e], d = dst[e];
        bf16x8 av = *(const bf16x8*)(A + (size_t)s * NFEATS + lane16 * 8);
        bf16x8 bv = *(const bf16x8*)(B + (size_t)d * NFEATS + lane16 * 8);
        float acc = 0.f;
#pragma unroll
        for (int j = 0; j < 8; ++j) {
            float h = bf2f(av[j]) + bf2f(bv[j]);
            h = fmaxf(h, 0.f);
            acc = fmaf(h, w2v[j], acc);
        }
        acc += __shfl_xor(acc, 1);
        acc += __shfl_xor(acc, 2);
        acc += __shfl_xor(acc, 4);
        acc += __shfl_xor(acc, 8);
        if (lane16 == 0) out[e] = acc + b2v;
    }
}

extern "C" void kernel_launch(void* const* d_in, const int* in_sizes, int n_in,
                              void* d_out, int out_size, void* d_ws, size_t ws_size,
                              hipStream_t stream) {
    const float* item = (const float*)d_in[0];
    const float* user = (const float*)d_in[1];
    const float* W1   = (const float*)d_in[2];
    const float* b1   = (const float*)d_in[3];
    const float* W2   = (const float*)d_in[4];
    const float* b2   = (const float*)d_in[5];
    const int*   src  = (const int*)d_in[6];
    const int*   dst  = (const int*)d_in[7];
    float* out = (float*)d_out;

    const int n_nodes = in_sizes[0] / NFEATS;
    const int n_edges = in_sizes[6];

    short* A = (short*)d_ws;                         // [n_nodes][128] bf16
    short* B = A + (size_t)n_nodes * NFEATS;         // [n_nodes][128] bf16

    const int nblk = (n_nodes + 127) / 128;
    precompute_kernel<<<nblk, 256, 0, stream>>>(item, W1, b1, A, n_nodes, 0, 1);
    precompute_kernel<<<nblk, 256, 0, stream>>>(user, W1, b1, B, n_nodes, 128, 0);

    edge_kernel<<<2048, 256, 0, stream>>>(A, B, src, dst, W2, b2, out, n_edges);
}

// Round 2
// 81.705 us; speedup vs baseline: 1.1213x; 1.1213x over previous
//
#include <hip/hip_runtime.h>
#include <hip/hip_bf16.h>

#define NFEATS 128

typedef __attribute__((ext_vector_type(8))) short bf16x8;
typedef __attribute__((ext_vector_type(4))) float f32x4;

__device__ inline short f2bf(float f) {
    union { float f; unsigned u; } c; c.f = f;
    unsigned u = c.u;
    return (short)((u + 0x7FFFu + ((u >> 16) & 1u)) >> 16);  // RNE
}
__device__ inline float bf2f(short v) {
    union { unsigned u; float f; } c;
    c.u = ((unsigned)(unsigned short)v) << 16;
    return c.f;
}

// Fused precompute for both tables:
//   blockIdx.y == 0: A[n,j] = sum_k item[n,k] * W1[j,   k] + b1[j]
//   blockIdx.y == 1: B[n,j] = sum_k user[n,k] * W1[j,128+k]
// Out stored bf16. One block = 128 rows x 128 cols, K=128 in one shot.
__global__ __launch_bounds__(256) void precompute_kernel(
    const float* __restrict__ item, const float* __restrict__ user,
    const float* __restrict__ W1, const float* __restrict__ b1,
    short* __restrict__ A, short* __restrict__ B, int n_nodes)
{
    const int which = blockIdx.y;
    const float* __restrict__ X = which ? user : item;
    short* __restrict__ Out = which ? B : A;
    const int k_off = which ? 128 : 0;

    // W tile in LDS, padded: stride 136 bf16 = 272 B (16B-aligned rows, bank stride 4)
    __shared__ short Wlds[128][136];
    const int tid = threadIdx.x;

    for (int idx = tid; idx < 128 * 128; idx += 256) {
        int j = idx >> 7, k = idx & 127;
        Wlds[j][k] = f2bf(W1[j * 256 + k_off + k]);
    }
    __syncthreads();

    const int wave = tid >> 6, lane = tid & 63;
    const int r16 = lane & 15, q = lane >> 4;       // q in 0..3
    const int row_base = blockIdx.x * 128 + wave * 32;

    // A-fragments: X rows -> bf16, lane holds X[row][kk*32 + q*8 + j], j=0..7
    bf16x8 afrag[2][4];
#pragma unroll
    for (int m = 0; m < 2; ++m) {
        int row = row_base + m * 16 + r16;
        if (row >= n_nodes) row = n_nodes - 1;      // clamp (stores predicated)
        const float* xr = X + (size_t)row * NFEATS;
#pragma unroll
        for (int kk = 0; kk < 4; ++kk) {
            int k0 = kk * 32 + q * 8;
            float4 lo = *(const float4*)(xr + k0);
            float4 hi = *(const float4*)(xr + k0 + 4);
            bf16x8 f;
            f[0] = f2bf(lo.x); f[1] = f2bf(lo.y); f[2] = f2bf(lo.z); f[3] = f2bf(lo.w);
            f[4] = f2bf(hi.x); f[5] = f2bf(hi.y); f[6] = f2bf(hi.z); f[7] = f2bf(hi.w);
            afrag[m][kk] = f;
        }
    }

    // Accumulators init with b1[col] (MFMA C-in accumulates); B-table has no bias
    f32x4 acc[2][8];
#pragma unroll
    for (int n = 0; n < 8; ++n) {
        float bv = which ? 0.f : b1[n * 16 + r16];
        f32x4 init = {bv, bv, bv, bv};
        acc[0][n] = init;
        acc[1][n] = init;
    }

#pragma unroll
    for (int n = 0; n < 8; ++n) {
#pragma unroll
        for (int kk = 0; kk < 4; ++kk) {
            // B operand: lane holds W[col=n*16+r16][k = kk*32 + q*8 + j]
            bf16x8 wf = *(const bf16x8*)&Wlds[n * 16 + r16][kk * 32 + q * 8];
            acc[0][n] = __builtin_amdgcn_mfma_f32_16x16x32_bf16(afrag[0][kk], wf, acc[0][n], 0, 0, 0);
            acc[1][n] = __builtin_amdgcn_mfma_f32_16x16x32_bf16(afrag[1][kk], wf, acc[1][n], 0, 0, 0);
        }
    }

    // C/D layout: col = lane&15, row = (lane>>4)*4 + r
#pragma unroll
    for (int m = 0; m < 2; ++m) {
#pragma unroll
        for (int r = 0; r < 4; ++r) {
            int row = row_base + m * 16 + q * 4 + r;
            if (row < n_nodes) {
                short* orow = Out + (size_t)row * NFEATS;
#pragma unroll
                for (int n = 0; n < 8; ++n)
                    orow[n * 16 + r16] = f2bf(acc[m][n][r]);
            }
        }
    }
}

// Edge stage: score[e] = dot(relu(A[src[e]] + B[dst[e]]), w2) + b2
// One quarter-wave (16 lanes) per edge, 2 edges in flight per iteration (MLP).
__global__ __launch_bounds__(256) void edge_kernel(
    const short* __restrict__ A, const short* __restrict__ B,
    const int* __restrict__ src, const int* __restrict__ dst,
    const float* __restrict__ W2, const float* __restrict__ b2,
    float* __restrict__ out, int n_edges)
{
    const int t = blockIdx.x * 256 + threadIdx.x;
    const int lane16 = threadIdx.x & 15;

    float w2v[8];
#pragma unroll
    for (int j = 0; j < 8; ++j) w2v[j] = W2[lane16 * 8 + j];
    const float b2v = b2[0];

    const int qw = t >> 4;
    const int nqw = (gridDim.x * 256) >> 4;

    for (int e0 = qw; e0 < n_edges; e0 += 2 * nqw) {
        const int e1 = e0 + nqw;
        const bool has1 = e1 < n_edges;

        int s0 = src[e0], d0 = dst[e0];
        int s1 = has1 ? src[e1] : s0;
        int d1 = has1 ? dst[e1] : d0;

        // 4 independent gathers in flight
        bf16x8 av0 = *(const bf16x8*)(A + (size_t)s0 * NFEATS + lane16 * 8);
        bf16x8 bv0 = *(const bf16x8*)(B + (size_t)d0 * NFEATS + lane16 * 8);
        bf16x8 av1 = *(const bf16x8*)(A + (size_t)s1 * NFEATS + lane16 * 8);
        bf16x8 bv1 = *(const bf16x8*)(B + (size_t)d1 * NFEATS + lane16 * 8);

        float acc0 = 0.f, acc1 = 0.f;
#pragma unroll
        for (int j = 0; j < 8; ++j) {
            float h0 = bf2f(av0[j]) + bf2f(bv0[j]);
            h0 = fmaxf(h0, 0.f);
            acc0 = fmaf(h0, w2v[j], acc0);
            float h1 = bf2f(av1[j]) + bf2f(bv1[j]);
            h1 = fmaxf(h1, 0.f);
            acc1 = fmaf(h1, w2v[j], acc1);
        }
#pragma unroll
        for (int sh = 1; sh <= 8; sh <<= 1) {
            acc0 += __shfl_xor(acc0, sh);
            acc1 += __shfl_xor(acc1, sh);
        }
        if (lane16 == 0) {
            out[e0] = acc0 + b2v;
            if (has1) out[e1] = acc1 + b2v;
        }
    }
}

extern "C" void kernel_launch(void* const* d_in, const int* in_sizes, int n_in,
                              void* d_out, int out_size, void* d_ws, size_t ws_size,
                              hipStream_t stream) {
    const float* item = (const float*)d_in[0];
    const float* user = (const float*)d_in[1];
    const float* W1   = (const float*)d_in[2];
    const float* b1   = (const float*)d_in[3];
    const float* W2   = (const float*)d_in[4];
    const float* b2   = (const float*)d_in[5];
    const int*   src  = (const int*)d_in[6];
    const int*   dst  = (const int*)d_in[7];
    float* out = (float*)d_out;

    const int n_nodes = in_sizes[0] / NFEATS;
    const int n_edges = in_sizes[6];

    short* A = (short*)d_ws;                         // [n_nodes][128] bf16
    short* B = A + (size_t)n_nodes * NFEATS;         // [n_nodes][128] bf16

    const int nblk = (n_nodes + 127) / 128;
    dim3 grid(nblk, 2);
    precompute_kernel<<<grid, 256, 0, stream>>>(item, user, W1, b1, A, B, n_nodes);

    edge_kernel<<<2048, 256, 0, stream>>>(A, B, src, dst, W2, b2, out, n_edges);
}